// Round 1
// baseline (4154.082 us; speedup 1.0000x reference)
//
#include <hip/hip_runtime.h>
#include <hip/hip_bf16.h>

#define T_TOK 8192
#define H_DIM 4096
#define N_EXP 8

#define BM 128
#define BN 128
#define BK 32
#define LDK 40  // padded LDS row stride in ushorts: 80B = 20 banks -> max 2-way aliasing (free)

typedef short bf16x8 __attribute__((ext_vector_type(8)));
typedef float f32x4 __attribute__((ext_vector_type(4)));

__device__ __forceinline__ unsigned short f2b(float f) {
  // round-to-nearest-even fp32 -> bf16 (inputs are finite)
  unsigned int u = __float_as_uint(f);
  u += 0x7fffu + ((u >> 16) & 1u);
  return (unsigned short)(u >> 16);
}

// ---------------- gate + top2 + per-expert token list build ----------------
__global__ __launch_bounds__(256) void gate_topk_kernel(
    const float* __restrict__ x, const float* __restrict__ gw,
    int* __restrict__ counts, int* __restrict__ lists) {
  int t = blockIdx.x;
  const float* xr = x + (size_t)t * H_DIM;
  double acc[N_EXP];
#pragma unroll
  for (int e = 0; e < N_EXP; ++e) acc[e] = 0.0;
  for (int h = threadIdx.x; h < H_DIM; h += 256) {
    float xv = xr[h];
#pragma unroll
    for (int e = 0; e < N_EXP; ++e) acc[e] += (double)xv * (double)gw[e * H_DIM + h];
  }
#pragma unroll
  for (int e = 0; e < N_EXP; ++e) {
#pragma unroll
    for (int off = 32; off > 0; off >>= 1) acc[e] += __shfl_down(acc[e], off, 64);
  }
  __shared__ double sacc[4][N_EXP];
  int wave = threadIdx.x >> 6;
  int lane = threadIdx.x & 63;
  if (lane == 0) {
#pragma unroll
    for (int e = 0; e < N_EXP; ++e) sacc[wave][e] = acc[e];
  }
  __syncthreads();
  if (threadIdx.x == 0) {
    double lg[N_EXP];
#pragma unroll
    for (int e = 0; e < N_EXP; ++e) lg[e] = sacc[0][e] + sacc[1][e] + sacc[2][e] + sacc[3][e];
    // top-2, ties -> lower index (strict >)
    int b1 = 0;
#pragma unroll
    for (int e = 1; e < N_EXP; ++e) if (lg[e] > lg[b1]) b1 = e;
    int b2 = (b1 == 0) ? 1 : 0;
#pragma unroll
    for (int e = 0; e < N_EXP; ++e) if (e != b1 && lg[e] > lg[b2]) b2 = e;
    int p1 = atomicAdd(&counts[b1], 1);
    lists[b1 * T_TOK + p1] = t;
    int p2 = atomicAdd(&counts[b2], 1);
    lists[b2 * T_TOK + p2] = t;
  }
}

// ---------------- grouped GEMM: out[t,:] += W[e] @ x[t] for t in list[e] ----------------
__global__ __launch_bounds__(256) void moe_gemm_kernel(
    const float* __restrict__ x, const float* __restrict__ w,
    const int* __restrict__ counts, const int* __restrict__ lists,
    float* __restrict__ out) {
  int e = blockIdx.z;
  int cnt = counts[e];
  int mt = blockIdx.x;
  if (mt * BM >= cnt) return;
  int nt = blockIdx.y;

  __shared__ unsigned short As[BM][LDK];
  __shared__ unsigned short Bs[BN][LDK];
  __shared__ int toks[BM];

  int tid = threadIdx.x;
  const int* list_e = lists + e * T_TOK;
  if (tid < BM) {
    int r = mt * BM + tid;
    toks[tid] = (r < cnt) ? list_e[r] : -1;
  }
  __syncthreads();

  // staging role: thread covers row srow, 16 k-elements starting at skc
  int srow = tid >> 1;
  int skc = (tid & 1) << 4;
  int tok = toks[srow];
  bool avalid = (tok >= 0);
  const float* aptr = x + (size_t)(avalid ? tok : 0) * H_DIM + skc;
  const float* bptr = w + (size_t)e * H_DIM * H_DIM + (size_t)(nt * BN + srow) * H_DIM + skc;

  // MFMA role
  int lane = tid & 63;
  int wv = tid >> 6;
  int wrow = (wv >> 1) << 6;  // 0 or 64
  int wcol = (wv & 1) << 6;   // 0 or 64
  int frow = lane & 15;
  int fko = (lane >> 4) << 3;  // 0,8,16,24

  f32x4 acc[4][4];
#pragma unroll
  for (int i = 0; i < 4; ++i)
#pragma unroll
    for (int j = 0; j < 4; ++j) acc[i][j] = (f32x4){0.f, 0.f, 0.f, 0.f};

  float4 av[4], bv[4];
#pragma unroll
  for (int i = 0; i < 4; ++i) {
    bv[i] = *(const float4*)(bptr + i * 4);
    av[i] = avalid ? *(const float4*)(aptr + i * 4) : make_float4(0.f, 0.f, 0.f, 0.f);
  }

  for (int k0 = 0; k0 < H_DIM; k0 += BK) {
    __syncthreads();  // all waves done reading LDS from previous iter
    // convert fp32 -> bf16 and write staged tile
    union { unsigned short us[8]; uint4 q; } pa0, pa1, pb0, pb1;
#pragma unroll
    for (int i = 0; i < 2; ++i) {
      pa0.us[i * 4 + 0] = f2b(av[i].x); pa0.us[i * 4 + 1] = f2b(av[i].y);
      pa0.us[i * 4 + 2] = f2b(av[i].z); pa0.us[i * 4 + 3] = f2b(av[i].w);
      pb0.us[i * 4 + 0] = f2b(bv[i].x); pb0.us[i * 4 + 1] = f2b(bv[i].y);
      pb0.us[i * 4 + 2] = f2b(bv[i].z); pb0.us[i * 4 + 3] = f2b(bv[i].w);
      pa1.us[i * 4 + 0] = f2b(av[i + 2].x); pa1.us[i * 4 + 1] = f2b(av[i + 2].y);
      pa1.us[i * 4 + 2] = f2b(av[i + 2].z); pa1.us[i * 4 + 3] = f2b(av[i + 2].w);
      pb1.us[i * 4 + 0] = f2b(bv[i + 2].x); pb1.us[i * 4 + 1] = f2b(bv[i + 2].y);
      pb1.us[i * 4 + 2] = f2b(bv[i + 2].z); pb1.us[i * 4 + 3] = f2b(bv[i + 2].w);
    }
    *(uint4*)&As[srow][skc] = pa0.q;
    *(uint4*)&As[srow][skc + 8] = pa1.q;
    *(uint4*)&Bs[srow][skc] = pb0.q;
    *(uint4*)&Bs[srow][skc + 8] = pb1.q;
    __syncthreads();

    // prefetch next k-slab while MFMAs run
    int kn = k0 + BK;
    if (kn >= H_DIM) kn = 0;  // dummy in-bounds load on last iter
#pragma unroll
    for (int i = 0; i < 4; ++i) {
      bv[i] = *(const float4*)(bptr + kn + i * 4);
      av[i] = avalid ? *(const float4*)(aptr + kn + i * 4) : make_float4(0.f, 0.f, 0.f, 0.f);
    }

    bf16x8 afr[4], bfr[4];
#pragma unroll
    for (int i = 0; i < 4; ++i) {
      afr[i] = *(const bf16x8*)&As[wrow + i * 16 + frow][fko];
      bfr[i] = *(const bf16x8*)&Bs[wcol + i * 16 + frow][fko];
    }
#pragma unroll
    for (int i = 0; i < 4; ++i)
#pragma unroll
      for (int j = 0; j < 4; ++j)
        acc[i][j] = __builtin_amdgcn_mfma_f32_16x16x32_bf16(afr[i], bfr[j], acc[i][j], 0, 0, 0);
  }

  // epilogue: scatter-add (each out element gets exactly 2 adds across experts)
  int crow = (lane >> 4) << 2;  // 0,4,8,12
  int ccol = lane & 15;
#pragma unroll
  for (int i = 0; i < 4; ++i) {
    int lr0 = wrow + i * 16 + crow;
#pragma unroll
    for (int r = 0; r < 4; ++r) {
      int tk = toks[lr0 + r];
      if (tk < 0) continue;
      float* orow = out + (size_t)tk * H_DIM + nt * BN + wcol + ccol;
#pragma unroll
      for (int j = 0; j < 4; ++j) atomicAdd(orow + j * 16, acc[i][j][r]);
    }
  }
}

extern "C" void kernel_launch(void* const* d_in, const int* in_sizes, int n_in,
                              void* d_out, int out_size, void* d_ws, size_t ws_size,
                              hipStream_t stream) {
  const float* x = (const float*)d_in[0];
  const float* gw = (const float*)d_in[1];
  const float* ew = (const float*)d_in[2];
  float* out = (float*)d_out;

  int* counts = (int*)d_ws;       // 8 ints (+8 pad)
  int* lists = counts + 16;       // 8 * 8192 ints

  hipMemsetAsync(d_ws, 0, 64, stream);
  hipMemsetAsync(d_out, 0, (size_t)out_size * sizeof(float), stream);

  gate_topk_kernel<<<T_TOK, 256, 0, stream>>>(x, gw, counts, lists);

  dim3 grid(T_TOK / BM, H_DIM / BN, N_EXP);
  moe_gemm_kernel<<<grid, 256, 0, stream>>>(x, ew, counts, lists, out);
}